// Round 1
// baseline (194.543 us; speedup 1.0000x reference)
//
#include <hip/hip_runtime.h>
#include <stdint.h>

typedef short bf16x8 __attribute__((ext_vector_type(8)));
typedef float f32x4 __attribute__((ext_vector_type(4)));

#define MFMA16(a,b,c) __builtin_amdgcn_mfma_f32_16x16x32_bf16((a),(b),(c),0,0,0)

static __device__ __forceinline__ unsigned short f2bf(float f){
  union { float f; unsigned int u; } v; v.f = f;
  unsigned int r = (v.u + 0x7fffu + ((v.u >> 16) & 1u)) >> 16;
  return (unsigned short)r;
}

#define NB 2
#define NS 4096
#define ND 1024
#define NR 128
#define NROWS 8192

// workspace byte offsets
#define XB_OFF   0u
#define WT_OFF   16777216u
#define QKVF_OFF 17563648u
#define QKVB_OFF 30146560u

// ---------------- prep: x (fp32) -> xb (bf16) ----------------
__global__ void k_prep_x(const float4* __restrict__ x4, uint4* __restrict__ xb4){
  int idx = blockIdx.x * 256 + threadIdx.x;      // 1,048,576 threads, 8 floats each
  float4 a = x4[idx*2], b = x4[idx*2+1];
  uint4 o;
  o.x = (unsigned)f2bf(a.x) | ((unsigned)f2bf(a.y) << 16);
  o.y = (unsigned)f2bf(a.z) | ((unsigned)f2bf(a.w) << 16);
  o.z = (unsigned)f2bf(b.x) | ((unsigned)f2bf(b.y) << 16);
  o.w = (unsigned)f2bf(b.z) | ((unsigned)f2bf(b.w) << 16);
  xb4[idx] = o;
}

// ---------------- prep: Wq/Wk/Wv [1024][128] fp32 -> Wt [384][1024] bf16 (transposed) ----------------
__global__ void k_prep_w(const float* __restrict__ Wq, const float* __restrict__ Wk,
                         const float* __restrict__ Wv, unsigned short* __restrict__ Wt){
  int idx = blockIdx.x * 256 + threadIdx.x;      // 393,216
  int m = idx >> 17;
  int r = idx & 131071;
  int n = r >> 10;
  int k = r & 1023;
  const float* W = (m == 0) ? Wq : (m == 1 ? Wk : Wv);
  Wt[idx] = f2bf(W[k*128 + n]);
}

// ---------------- GEMM: xb[8192][1024] @ Wt^T -> QKVf [3][8192][128] fp32 ----------------
__global__ __launch_bounds__(256,4)
void k_gemm_qkv(const unsigned short* __restrict__ xb,
                const unsigned short* __restrict__ Wt,
                float* __restrict__ QKVf){
  __shared__ __align__(16) unsigned short As[64*48];  // rows 64, 32 cols + pad to 48
  __shared__ __align__(16) unsigned short Bs[64*48];
  int bx = blockIdx.x;
  int m0 = (bx & 127) << 6;
  int n0 = (bx >> 7) << 6;
  int t = threadIdx.x;
  int lane = t & 63, w = t >> 6;
  int lq = lane & 15, g = lane >> 4;
  f32x4 acc[4];
  #pragma unroll
  for (int mi = 0; mi < 4; ++mi) acc[mi] = f32x4{0.f,0.f,0.f,0.f};
  int srow = t >> 2, scg = (t & 3) << 3;
  for (int k0 = 0; k0 < 1024; k0 += 32){
    uint4 va = *(const uint4*)(xb + (size_t)(m0 + srow)*1024 + k0 + scg);
    uint4 vb = *(const uint4*)(Wt + (size_t)(n0 + srow)*1024 + k0 + scg);
    *(uint4*)(As + srow*48 + scg) = va;
    *(uint4*)(Bs + srow*48 + scg) = vb;
    __syncthreads();
    bf16x8 bfr = *(const bf16x8*)(Bs + (w*16 + lq)*48 + g*8);
    #pragma unroll
    for (int mi = 0; mi < 4; ++mi){
      bf16x8 afr = *(const bf16x8*)(As + (mi*16 + lq)*48 + g*8);
      acc[mi] = MFMA16(afr, bfr, acc[mi]);
    }
    __syncthreads();
  }
  int ncol = n0 + w*16 + lq;
  int mat = ncol >> 7, c = ncol & 127;
  float* op = QKVf + (size_t)mat*NROWS*128 + c;
  #pragma unroll
  for (int mi = 0; mi < 4; ++mi){
    int rbase = m0 + mi*16 + 4*g;
    #pragma unroll
    for (int r = 0; r < 4; ++r)
      op[(size_t)(rbase + r)*128] = acc[mi][r];
  }
}

// ---------------- RoPE + bf16 convert; Q pre-scaled by 1/8 ----------------
__global__ void k_rope(const float* __restrict__ QKVf, unsigned short* __restrict__ QKVb){
  int idx = blockIdx.x * 256 + threadIdx.x;   // 524,288
  int row = idx >> 6, i = idx & 63;
  int s = row & 4095;
  double inv = exp((double)i * -0.14391156831212805);   // ln(10000)/64
  double ang = (double)s * inv;
  float cf = (float)cos(ang), sf = (float)sin(ang);
  const float* Qf = QKVf;
  const float* Kf = QKVf + (size_t)NROWS*128;
  const float* Vf = QKVf + (size_t)2*NROWS*128;
  size_t base = (size_t)row * 128;
  float q1 = Qf[base+i], q2 = Qf[base+i+64];
  float k1 = Kf[base+i], k2 = Kf[base+i+64];
  float v1 = Vf[base+i], v2 = Vf[base+i+64];
  unsigned short* Qb = QKVb;
  unsigned short* Kb = QKVb + (size_t)NROWS*128;
  unsigned short* Vb = QKVb + (size_t)2*NROWS*128;
  Qb[base+i]    = f2bf((q1*cf - q2*sf) * 0.125f);
  Qb[base+i+64] = f2bf((q2*cf + q1*sf) * 0.125f);
  Kb[base+i]    = f2bf(k1*cf - k2*sf);
  Kb[base+i+64] = f2bf(k2*cf + k1*sf);
  Vb[base+i]    = f2bf(v1);
  Vb[base+i+64] = f2bf(v2);
}

// online softmax update for one score mat; returns packed P fragment
static __device__ __forceinline__ bf16x8 online_update(const f32x4* S, float& m, float& ssum,
                                                       f32x4* O, int g){
  float tmax = fmaxf(fmaxf(fmaxf(S[0][0],S[0][1]), fmaxf(S[0][2],S[0][3])),
                     fmaxf(fmaxf(S[1][0],S[1][1]), fmaxf(S[1][2],S[1][3])));
  tmax = fmaxf(tmax, __shfl_xor(tmax, 16));
  tmax = fmaxf(tmax, __shfl_xor(tmax, 32));
  float mnew = fmaxf(m, tmax);
  float p[8]; float psum = 0.f;
  #pragma unroll
  for (int h = 0; h < 2; ++h)
    #pragma unroll
    for (int r = 0; r < 4; ++r){
      float e = __expf(S[h][r] - mnew);
      p[h*4 + r] = e; psum += e;
    }
  psum += __shfl_xor(psum, 16);
  psum += __shfl_xor(psum, 32);
  if (__any(tmax > m)){
    float ce = __expf(m - mnew);
    ssum = ssum * ce + psum;
    m = mnew;
    float cr[4];
    #pragma unroll
    for (int r = 0; r < 4; ++r) cr[r] = __shfl(ce, 4*g + r);
    #pragma unroll
    for (int dg = 0; dg < 8; ++dg){
      O[dg][0] *= cr[0]; O[dg][1] *= cr[1]; O[dg][2] *= cr[2]; O[dg][3] *= cr[3];
    }
  } else {
    ssum += psum;
  }
  bf16x8 P;
  #pragma unroll
  for (int j = 0; j < 8; ++j) P[j] = (short)f2bf(p[j]);
  return P;
}

// ---------------- flash differential attention ----------------
// grid 512: block = (batch, 16-query tile); 4 waves = 4 key chunks of 1024
__global__ __launch_bounds__(256,2)
void k_flash(const unsigned short* __restrict__ QKVb,
             const float* __restrict__ lq1, const float* __restrict__ lq2,
             const float* __restrict__ lk1, const float* __restrict__ lk2,
             float* __restrict__ out){
  __shared__ __align__(16) char lds[32768];       // 4 waves x 8KB V-tiles; reused as combine buf
  __shared__ float stats[4][16][4];
  int bid = blockIdx.x;
  int b = bid >> 8, qt = bid & 255;
  int q0 = qt << 4;
  int t = threadIdx.x;
  int w = t >> 6, lane = t & 63;
  int lq = lane & 15, g = lane >> 4;
  const uint4* Qb4 = (const uint4*)QKVb;
  const uint4* Kb4 = (const uint4*)(QKVb + (size_t)NROWS*128);
  const uint4* Vb4 = (const uint4*)(QKVb + (size_t)2*NROWS*128);
  size_t rowbase = (size_t)b * 4096;

  float l1s = 0.f, l2s = 0.f;
  for (int i = 0; i < 64; ++i){ l1s += lq1[i]*lk1[i]; l2s += lq2[i]*lk2[i]; }
  float lam = __expf(l1s) - __expf(l2s) + 0.3555090675909693f;

  bf16x8 qf[4];
  #pragma unroll
  for (int f = 0; f < 4; ++f){
    uint4 v = Qb4[(rowbase + q0 + lq)*16 + 4*f + g];
    qf[f] = *(bf16x8*)&v;
  }
  f32x4 O1[8], O2[8];
  #pragma unroll
  for (int dg = 0; dg < 8; ++dg){ O1[dg] = f32x4{0.f,0.f,0.f,0.f}; O2[dg] = f32x4{0.f,0.f,0.f,0.f}; }
  float m1 = -1e30f, m2 = -1e30f, s1 = 0.f, s2 = 0.f;

  char* vlds = lds + w*8192;
  unsigned vbase = (unsigned)(uintptr_t)vlds;
  int key0base = w << 10;
  // V LDS subtile layout: elem (k,d) at byte (d>>4)*1024 + (k>>2)*128 + (k&3)*32 + (d&15)*2
  int vwoff = (lq >> 1)*1024 + g*32 + (lq & 1)*16;   // write addr for (row=4c+g, colgrp=lq)

  uint4 vreg[8];
  #pragma unroll
  for (int c = 0; c < 8; ++c)
    vreg[c] = Vb4[(rowbase + key0base + 4*c + g)*16 + lq];
  #pragma unroll
  for (int c = 0; c < 8; ++c)
    *(uint4*)(vlds + vwoff + c*128) = vreg[c];

  for (int it = 0; it < 32; ++it){
    int key0 = key0base + it*32;
    bf16x8 kf[2][4];
    #pragma unroll
    for (int h = 0; h < 2; ++h)
      #pragma unroll
      for (int f = 0; f < 4; ++f){
        uint4 v = Kb4[(rowbase + key0 + h*16 + lq)*16 + 4*f + g];
        kf[h][f] = *(bf16x8*)&v;
      }
    if (it < 31){
      #pragma unroll
      for (int c = 0; c < 8; ++c)
        vreg[c] = Vb4[(rowbase + key0 + 32 + 4*c + g)*16 + lq];
    }
    // swapped scores: D[key][q], lane holds S[key=4g+r][q=lq]
    f32x4 S1[2], S2[2];
    #pragma unroll
    for (int h = 0; h < 2; ++h){
      f32x4 z1 = f32x4{0.f,0.f,0.f,0.f};
      z1 = MFMA16(kf[h][0], qf[0], z1);
      S1[h] = MFMA16(kf[h][1], qf[1], z1);
      f32x4 z2 = f32x4{0.f,0.f,0.f,0.f};
      z2 = MFMA16(kf[h][2], qf[2], z2);
      S2[h] = MFMA16(kf[h][3], qf[3], z2);
    }
    bf16x8 P1 = online_update(S1, m1, s1, O1, g);
    bf16x8 P2 = online_update(S2, m2, s2, O2, g);

    // PV: V fragments via hardware transpose-read from LDS
    unsigned long long tr0[8], tr1[8];
    asm volatile("s_waitcnt lgkmcnt(0)" ::: "memory");
    #pragma unroll
    for (int dg = 0; dg < 8; ++dg){
      unsigned a = vbase + dg*1024 + lane*8;
      asm volatile("ds_read_b64_tr_b16 %0, %2 offset:0\n\t"
                   "ds_read_b64_tr_b16 %1, %2 offset:512"
                   : "=&v"(tr0[dg]), "=&v"(tr1[dg]) : "v"(a) : "memory");
    }
    asm volatile("s_waitcnt lgkmcnt(0)" ::: "memory");
    __builtin_amdgcn_sched_barrier(0);
    #pragma unroll
    for (int dg = 0; dg < 8; ++dg){
      union { unsigned long long u[2]; bf16x8 v; } vv;
      vv.u[0] = tr0[dg]; vv.u[1] = tr1[dg];
      O1[dg] = MFMA16(P1, vv.v, O1[dg]);
      O2[dg] = MFMA16(P2, vv.v, O2[dg]);
    }
    if (it < 31){
      #pragma unroll
      for (int c = 0; c < 8; ++c)
        *(uint4*)(vlds + vwoff + c*128) = vreg[c];
    }
  }

  // ---- cross-wave combine (key-split reduction), phased to keep LDS <= 33KB ----
  __syncthreads();
  float* cbuf = (float*)lds;     // [16 q][4 w][128 d]
  #pragma unroll
  for (int dg = 0; dg < 8; ++dg){
    int d = dg*16 + lq;
    #pragma unroll
    for (int r = 0; r < 4; ++r)
      cbuf[((4*g + r)*4 + w)*128 + d] = O1[dg][r];
  }
  if (lane < 16){
    stats[w][lane][0] = m1; stats[w][lane][1] = s1;
    stats[w][lane][2] = m2; stats[w][lane][3] = s2;
  }
  __syncthreads();
  int d4 = (t & 31) << 2;
  int qs = t >> 5;
  float res1[2][4];
  #pragma unroll
  for (int pass = 0; pass < 2; ++pass){
    int qq = qs + pass*8;
    float M1 = -1e30f;
    #pragma unroll
    for (int w4 = 0; w4 < 4; ++w4) M1 = fmaxf(M1, stats[w4][qq][0]);
    float L1 = 0.f, a1[4] = {0.f,0.f,0.f,0.f};
    #pragma unroll
    for (int w4 = 0; w4 < 4; ++w4){
      float e1 = __expf(stats[w4][qq][0] - M1);
      L1 += stats[w4][qq][1] * e1;
      const float4 o1 = *(const float4*)&cbuf[(qq*4 + w4)*128 + d4];
      a1[0] += o1.x*e1; a1[1] += o1.y*e1; a1[2] += o1.z*e1; a1[3] += o1.w*e1;
    }
    float r1 = 1.f / L1;
    res1[pass][0] = a1[0]*r1; res1[pass][1] = a1[1]*r1;
    res1[pass][2] = a1[2]*r1; res1[pass][3] = a1[3]*r1;
  }
  __syncthreads();
  #pragma unroll
  for (int dg = 0; dg < 8; ++dg){
    int d = dg*16 + lq;
    #pragma unroll
    for (int r = 0; r < 4; ++r)
      cbuf[((4*g + r)*4 + w)*128 + d] = O2[dg][r];
  }
  __syncthreads();
  #pragma unroll
  for (int pass = 0; pass < 2; ++pass){
    int qq = qs + pass*8;
    float M2 = -1e30f;
    #pragma unroll
    for (int w4 = 0; w4 < 4; ++w4) M2 = fmaxf(M2, stats[w4][qq][2]);
    float L2 = 0.f, a2[4] = {0.f,0.f,0.f,0.f};
    #pragma unroll
    for (int w4 = 0; w4 < 4; ++w4){
      float e2 = __expf(stats[w4][qq][2] - M2);
      L2 += stats[w4][qq][3] * e2;
      const float4 o2 = *(const float4*)&cbuf[(qq*4 + w4)*128 + d4];
      a2[0] += o2.x*e2; a2[1] += o2.y*e2; a2[2] += o2.z*e2; a2[3] += o2.w*e2;
    }
    float r2 = lam / L2;
    float4 res;
    res.x = res1[pass][0] - a2[0]*r2;
    res.y = res1[pass][1] - a2[1]*r2;
    res.z = res1[pass][2] - a2[2]*r2;
    res.w = res1[pass][3] - a2[3]*r2;
    *(float4*)&out[(rowbase + q0 + qq)*128 + d4] = res;
  }
}

extern "C" void kernel_launch(void* const* d_in, const int* in_sizes, int n_in,
                              void* d_out, int out_size, void* d_ws, size_t ws_size,
                              hipStream_t stream){
  const float* x   = (const float*)d_in[0];
  const float* Wq  = (const float*)d_in[1];
  const float* Wk  = (const float*)d_in[2];
  const float* Wv  = (const float*)d_in[3];
  const float* lq1 = (const float*)d_in[4];
  const float* lq2 = (const float*)d_in[5];
  const float* lk1 = (const float*)d_in[6];
  const float* lk2 = (const float*)d_in[7];
  float* out = (float*)d_out;
  char* ws = (char*)d_ws;

  unsigned short* xb   = (unsigned short*)(ws + XB_OFF);
  unsigned short* Wt   = (unsigned short*)(ws + WT_OFF);
  float*          QKVf = (float*)(ws + QKVF_OFF);
  unsigned short* QKVb = (unsigned short*)(ws + QKVB_OFF);

  k_prep_x<<<dim3(4096), dim3(256), 0, stream>>>((const float4*)x, (uint4*)xb);
  k_prep_w<<<dim3(1536), dim3(256), 0, stream>>>(Wq, Wk, Wv, Wt);
  k_gemm_qkv<<<dim3(768), dim3(256), 0, stream>>>(xb, Wt, QKVf);
  k_rope<<<dim3(2048), dim3(256), 0, stream>>>(QKVf, QKVb);
  k_flash<<<dim3(512), dim3(256), 0, stream>>>(QKVb, lq1, lq2, lk1, lk2, out);
}